// Round 2
// 700.276 us; speedup vs baseline: 1.0431x; 1.0431x over previous
//
#include <hip/hip_runtime.h>
#include <hip/hip_bf16.h>

// DeStationaryAttention: y = softmax((xq Wq + bq)(xk Wk + bk)^T / 8) (xv Wv + bv)
// B=4 H=8 L=2048 Dk=64 Dm=512. All I/O float32.
// Outputs: out [4,2048,512] ++ attn [4,8,2048,2048], f32.
// Internal workspace Q/K/V^T kept in bf16 for MFMA.

using u16 = unsigned short;
using u32 = unsigned int;

typedef __attribute__((ext_vector_type(4))) float  f32x4;
typedef __attribute__((ext_vector_type(8))) short  s16x8;
typedef __attribute__((ext_vector_type(4))) short  s16x4;
typedef __attribute__((ext_vector_type(2))) unsigned int u32x2;
typedef __attribute__((ext_vector_type(4))) unsigned int u32x4;

#define MFMA16(a,b,c) __builtin_amdgcn_mfma_f32_16x16x32_bf16(a,b,c,0,0,0)

#if __has_builtin(__builtin_amdgcn_mfma_f32_16x16x16bf16_1k)
#define MFMA1616(a,b,c) __builtin_amdgcn_mfma_f32_16x16x16bf16_1k(a,b,c,0,0,0)
#else
__device__ __forceinline__ f32x4 MFMA1616(s16x4 a, s16x4 b, f32x4 c){
  asm("v_mfma_f32_16x16x16_bf16 %0, %1, %2, %0" : "+v"(c) : "v"(a), "v"(b));
  return c;
}
#endif

__device__ __forceinline__ u16 f2bf(float f){
  u32 x; __builtin_memcpy(&x, &f, 4);
  x += 0x7FFFu + ((x >> 16) & 1u);   // RNE
  return (u16)(x >> 16);
}
__device__ __forceinline__ u32 pk2(float a, float b){
  return (u32)f2bf(a) | ((u32)f2bf(b) << 16);
}
#if __has_builtin(__builtin_amdgcn_exp2f)
__device__ __forceinline__ float ex2(float x){ return __builtin_amdgcn_exp2f(x); }
#else
__device__ __forceinline__ float ex2(float x){ return exp2f(x); }
#endif

// async global->LDS, 16B per lane; dest is wave-uniform base (+ lane*16 in HW)
__device__ __forceinline__ void async16(const u16* src, char* wavebase, int lane){
#if __has_builtin(__builtin_amdgcn_global_load_lds)
  __builtin_amdgcn_global_load_lds(
      (const __attribute__((address_space(1))) unsigned int*)src,
      (__attribute__((address_space(3))) unsigned int*)wavebase, 16, 0, 0);
#else
  *(u32x4*)(wavebase + lane*16) = *(const u32x4*)src;
#endif
}

// softmax scale: 1/sqrt(64) folded with log2(e) for native v_exp_f32 (2^x)
#define SCALE2 0.18033688f

// ---------------------------------------------------------------------------
// Kernel 0: transpose+convert the three 512x512 f32 weights: Wt[n][k]=bf16(W[k][n])
// ---------------------------------------------------------------------------
__global__ void wt_kernel(const float* __restrict__ W0, const float* __restrict__ W1,
                          const float* __restrict__ W2,
                          u16* __restrict__ T0, u16* __restrict__ T1, u16* __restrict__ T2){
  const float* W = blockIdx.z==0 ? W0 : (blockIdx.z==1 ? W1 : W2);
  u16*         T = blockIdx.z==0 ? T0 : (blockIdx.z==1 ? T1 : T2);
  __shared__ u16 t[32][33];
  int x = threadIdx.x, y0 = threadIdx.y;           // 32 x 8
  int bx = blockIdx.x*32, by = blockIdx.y*32;
  #pragma unroll
  for (int i=0;i<4;i++){ int y=y0+i*8; t[y][x] = f2bf(W[(by+y)*512 + bx + x]); }
  __syncthreads();
  #pragma unroll
  for (int i=0;i<4;i++){ int y=y0+i*8; T[(bx+y)*512 + by + x] = t[x][y]; }
}

// ---------------------------------------------------------------------------
// Kernel 1: fused QKV projection GEMMs (K=512), 128x128 tiles, 4 waves/block.
// (unchanged)
// ---------------------------------------------------------------------------
__global__ __launch_bounds__(256,2) void proj_kernel(
    const float* __restrict__ q_in, const float* __restrict__ k_in, const float* __restrict__ v_in,
    const u16* __restrict__ Wt,
    const float* __restrict__ bq, const float* __restrict__ bk, const float* __restrict__ bv,
    u16* __restrict__ Qo, u16* __restrict__ Ko, u16* __restrict__ Vto)
{
  const int mode = blockIdx.z;
  const int lt = blockIdx.x;       // 0..63
  const int nt = blockIdx.y;       // 0..3
  const float* Xf   = mode==0 ? q_in : (mode==1 ? k_in : v_in);
  const u16*   Wm   = Wt + (size_t)mode*512*512;
  const float* bias = mode==0 ? bq : (mode==1 ? bk : bv);

  __shared__ __align__(16) u16 As[128*32];
  __shared__ __align__(16) u16 Bs[128*32];

  u16* Wdst = (mode<2) ? As : Bs;
  u16* Xdst = (mode<2) ? Bs : As;
  const int wrow0 = nt*128, xrow0 = lt*128;

  const int t = threadIdx.x;
  const int w = t>>6, lane = t&63, l16 = lane&15, quad = lane>>4;
  const int am = (w&1)*64, bn = (w>>1)*64;

  f32x4 acc[4][4];
  #pragma unroll
  for (int i=0;i<4;i++)
    #pragma unroll
    for (int j=0;j<4;j++) acc[i][j] = (f32x4){0.f,0.f,0.f,0.f};

  for (int kk=0; kk<512; kk+=32){
    __syncthreads();
    #pragma unroll
    for (int j=0;j<2;j++){
      int id = j*256 + t;
      int row = id>>2, c4 = id&3;
      int sw = c4 ^ (row&3) ^ ((row>>2)&3);
      u32x4 vw = *(const u32x4*)(Wm + (size_t)(wrow0+row)*512 + kk + c4*8);
      *(u32x4*)((char*)Wdst + row*64 + sw*16) = vw;
      const float* xp = Xf + (size_t)(xrow0+row)*512 + kk + c4*8;
      f32x4 x0 = *(const f32x4*)xp;
      f32x4 x1 = *(const f32x4*)(xp+4);
      u32x4 vx = { pk2(x0[0],x0[1]), pk2(x0[2],x0[3]),
                   pk2(x1[0],x1[1]), pk2(x1[2],x1[3]) };
      *(u32x4*)((char*)Xdst + row*64 + sw*16) = vx;
    }
    __syncthreads();
    s16x8 fa[4], fb[4];
    #pragma unroll
    for (int i=0;i<4;i++){
      int ra = am + i*16 + l16;
      fa[i] = *(const s16x8*)((const char*)As + ra*64 + ((quad ^ (ra&3) ^ ((ra>>2)&3))*16));
      int rb = bn + i*16 + l16;
      fb[i] = *(const s16x8*)((const char*)Bs + rb*64 + ((quad ^ (rb&3) ^ ((rb>>2)&3))*16));
    }
    #pragma unroll
    for (int i=0;i<4;i++)
      #pragma unroll
      for (int j=0;j<4;j++)
        acc[i][j] = MFMA16(fa[i], fb[j], acc[i][j]);
  }

  if (mode < 2){
    u16* Out = mode==0 ? Qo : Ko;
    #pragma unroll
    for (int i=0;i<4;i++){
      int n0 = nt*128 + am + i*16 + quad*4;
      float b4[4];
      #pragma unroll
      for (int r=0;r<4;r++) b4[r] = bias[n0+r];
      int h = n0>>6, d0 = n0&63;
      #pragma unroll
      for (int j=0;j<4;j++){
        int lg = lt*128 + bn + j*16 + l16;
        int b = lg>>11, ll = lg&2047;
        u32x2 pk = { pk2(acc[i][j][0]+b4[0], acc[i][j][1]+b4[1]),
                     pk2(acc[i][j][2]+b4[2], acc[i][j][3]+b4[3]) };
        *(u32x2*)(Out + ((size_t)(((b<<3)+h)*2048 + ll)<<6) + d0) = pk;
      }
    }
  } else {
    #pragma unroll
    for (int j=0;j<4;j++){
      int nv = nt*128 + bn + j*16 + l16;
      float bvv = bias[nv];
      int h = nv>>6, d = nv&63;
      #pragma unroll
      for (int i=0;i<4;i++){
        int lg = lt*128 + am + i*16 + quad*4;
        int b = lg>>11, ll = lg&2047;
        u32x2 pk = { pk2(acc[i][j][0]+bvv, acc[i][j][1]+bvv),
                     pk2(acc[i][j][2]+bvv, acc[i][j][3]+bvv) };
        *(u32x2*)(Vto + ((size_t)(((b<<3)+h)*64 + d)<<11) + ll) = pk;
      }
    }
  }
}

// ---------------------------------------------------------------------------
// Kernel 2: attention, restructured (512 threads / 8 waves, 1 barrier per
// k-tile, register-resident Q and P-fragments, double-buffered K/V staging).
// Buffer pointers computed from `cur` each iteration (no LDS pointer arrays —
// hipcc rejects addrspacecast static initializers).
// ---------------------------------------------------------------------------
__global__ __launch_bounds__(512,4) void attn_kernel(
    const u16* __restrict__ Q, const u16* __restrict__ K, const u16* __restrict__ Vt,
    float* __restrict__ out, float* __restrict__ attn)
{
  const int qt = blockIdx.x;                   // 0..15
  const int bh = blockIdx.z*8 + blockIdx.y;    // b*8+h
  const int q0 = qt*128;
  const u16* Qg = Q  + (size_t)bh*2048*64;
  const u16* Kg = K  + (size_t)bh*2048*64;
  const u16* Vg = Vt + (size_t)bh*64*2048;
  float* attng = attn + ((size_t)bh*2048 + q0)*2048;

  __shared__ __align__(128) char smem[65536];
  float* Ls = (float*)(smem + 49152);          // aliases Vs buf1; dead before use
  float* Os = (float*)smem;                    // [128][68] f32, end only

  const int t = threadIdx.x;
  const int w = t>>6, lane = t&63, l16 = lane&15, quad = lane>>4;
  const int coff = (w&1)*64, roff = (w>>1)*32;

  if (t < 128) Ls[t] = 0.f;
  __syncthreads();

  // Q fragments resident in registers: rows roff..roff+31, full K=64
  s16x8 qf[2][2];
  #pragma unroll
  for (int kc=0;kc<2;kc++)
    #pragma unroll
    for (int ri=0;ri<2;ri++)
      qf[kc][ri] = *(const s16x8*)(Qg + (size_t)(q0 + roff + ri*16 + l16)*64 + (kc*4+quad)*8);

  // prefetch tile 0 of K,V into buffer 0 (consumed at start of pass 2;
  // in flight across all of pass 1, drained at the pass-boundary barrier)
  #pragma unroll
  for (int j=0;j<2;j++){
    int id = j*512 + t; int row = id>>3, ch = id&7;
    async16(Kg + (size_t)row*64 + ((ch ^ (row&7))*8), smem + (j*512 + w*64)*16, lane);
  }
  #pragma unroll
  for (int j=0;j<2;j++){
    int id = j*512 + t; int row = id>>4, ch = id&15;
    async16(Vg + (size_t)row*2048 + ((ch ^ (row&15))*8), smem + 32768 + (j*512 + w*64)*16, lane);
  }

  // ------------------------------ pass 1: row sums (no barriers) -----------
  float lsum[2] = {0.f, 0.f};
  for (int kt=0; kt<16; kt++){
    f32x4 s[4][2];
    #pragma unroll
    for (int ci=0;ci<4;ci++)
      #pragma unroll
      for (int ri=0;ri<2;ri++) s[ci][ri] = (f32x4){0.f,0.f,0.f,0.f};
    #pragma unroll
    for (int kc=0;kc<2;kc++){
      #pragma unroll
      for (int ci=0;ci<4;ci++){
        int rc = kt*128 + coff + ci*16 + l16;
        s16x8 fa = *(const s16x8*)(Kg + (size_t)rc*64 + (kc*4+quad)*8);
        #pragma unroll
        for (int ri=0;ri<2;ri++) s[ci][ri] = MFMA16(fa, qf[kc][ri], s[ci][ri]);
      }
    }
    #pragma unroll
    for (int ri=0;ri<2;ri++){
      float ps = 0.f;
      #pragma unroll
      for (int ci=0;ci<4;ci++)
        #pragma unroll
        for (int r=0;r<4;r++) ps += ex2(s[ci][ri][r]*SCALE2);
      lsum[ri] += ps;
    }
  }
  #pragma unroll
  for (int ri=0;ri<2;ri++){
    float v = lsum[ri];
    v += __shfl_xor(v, 16, 64);
    v += __shfl_xor(v, 32, 64);
    if (quad == 0) atomicAdd(&Ls[roff + ri*16 + l16], v);
  }
  __syncthreads();                 // Ls complete; prologue prefetch drained
  float rinv[2];
  #pragma unroll
  for (int ri=0;ri<2;ri++) rinv[ri] = 1.0f / Ls[roff + ri*16 + l16];
  __syncthreads();                 // all Ls reads done before Vs buf1 prefetch

  // ------------------------------ pass 2 -----------------------------------
  f32x4 o[2][4];
  #pragma unroll
  for (int ri=0;ri<2;ri++)
    #pragma unroll
    for (int ni=0;ni<4;ni++) o[ri][ni] = (f32x4){0.f,0.f,0.f,0.f};

  int cur = 0;
  for (int kt=0; kt<16; kt++){
    char* Kc = smem + cur*16384;
    char* Vc = smem + 32768 + cur*16384;
    char* Kn = smem + (cur^1)*16384;
    char* Vn = smem + 32768 + (cur^1)*16384;
    if (kt < 15){                  // issue prefetch for kt+1 (async)
      #pragma unroll
      for (int j=0;j<2;j++){
        int id = j*512 + t; int row = id>>3, ch = id&7;
        async16(Kg + (size_t)((kt+1)*128+row)*64 + ((ch ^ (row&7))*8),
                Kn + (j*512 + w*64)*16, lane);
      }
      #pragma unroll
      for (int j=0;j<2;j++){
        int id = j*512 + t; int row = id>>4, ch = id&15;
        async16(Vg + (size_t)row*2048 + (kt+1)*128 + ((ch ^ (row&15))*8),
                Vn + (j*512 + w*64)*16, lane);
      }
    }
    // S^T = K Q^T from LDS K + register Q
    f32x4 s[4][2];
    #pragma unroll
    for (int ci=0;ci<4;ci++)
      #pragma unroll
      for (int ri=0;ri<2;ri++) s[ci][ri] = (f32x4){0.f,0.f,0.f,0.f};
    #pragma unroll
    for (int kc=0;kc<2;kc++){
      #pragma unroll
      for (int ci=0;ci<4;ci++){
        int rc = coff + ci*16 + l16;
        s16x8 fa = *(const s16x8*)(Kc + rc*128 + (((kc*4+quad) ^ (rc&7))*16));
        #pragma unroll
        for (int ri=0;ri<2;ri++) s[ci][ri] = MFMA16(fa, qf[kc][ri], s[ci][ri]);
      }
    }
    // softmax weights: f32 straight to global, bf16 packed A-frags in regs
    s16x4 pa[4][2];
    #pragma unroll
    for (int ci=0;ci<4;ci++){
      #pragma unroll
      for (int ri=0;ri<2;ri++){
        f32x4 e;
        #pragma unroll
        for (int r=0;r<4;r++) e[r] = ex2(s[ci][ri][r]*SCALE2)*rinv[ri];
        int rr = roff + ri*16 + l16;
        int c0 = coff + ci*16 + quad*4;
        *(f32x4*)(attng + (size_t)rr*2048 + kt*128 + c0) = e;
        s16x4 p;
        #pragma unroll
        for (int r=0;r<4;r++) p[r] = (short)f2bf(e[r]);
        pa[ci][ri] = p;
      }
    }
    // O_partial += W V over this wave's c-half (A-frags = pa, registers)
    #pragma unroll
    for (int cc=0;cc<4;cc++){
      #pragma unroll
      for (int ni=0;ni<4;ni++){
        int dd = ni*16 + l16;
        int ch = ((coff>>3) + cc*2 + (quad>>1)) ^ (dd&15);
        s16x4 vb = *(const s16x4*)(Vc + dd*256 + ch*16 + (quad&1)*8);
        #pragma unroll
        for (int ri=0;ri<2;ri++) o[ri][ni] = MFMA1616(pa[cc][ri], vb, o[ri][ni]);
      }
    }
    __syncthreads();               // drain prefetch; order buffer reuse
    cur ^= 1;
  }

  // cross-wave reduction of c-half partials (pairs w, w^1 share roff)
  if (w & 1){
    #pragma unroll
    for (int ri=0;ri<2;ri++)
      #pragma unroll
      for (int ni=0;ni<4;ni++)
        #pragma unroll
        for (int r=0;r<4;r++)
          Os[(roff + ri*16 + quad*4 + r)*68 + ni*16 + l16] = o[ri][ni][r];
  }
  __syncthreads();
  if (!(w & 1)){
    float* og = out + ((size_t)(bh>>3)*2048 + q0)*512 + (bh&7)*64;
    #pragma unroll
    for (int ri=0;ri<2;ri++)
      #pragma unroll
      for (int ni=0;ni<4;ni++)
        #pragma unroll
        for (int r=0;r<4;r++){
          int rr = roff + ri*16 + quad*4 + r;
          int dd = ni*16 + l16;
          og[(size_t)rr*512 + dd] = o[ri][ni][r] + Os[rr*68 + dd];
        }
  }
}

// ---------------------------------------------------------------------------
extern "C" void kernel_launch(void* const* d_in, const int* in_sizes, int n_in,
                              void* d_out, int out_size, void* d_ws, size_t ws_size,
                              hipStream_t stream) {
  (void)in_sizes; (void)n_in; (void)out_size; (void)ws_size;
  const float* q_in = (const float*)d_in[0];
  const float* k_in = (const float*)d_in[1];
  const float* v_in = (const float*)d_in[2];
  const float* Wq   = (const float*)d_in[3];
  const float* bq   = (const float*)d_in[4];
  const float* Wk   = (const float*)d_in[5];
  const float* bk   = (const float*)d_in[6];
  const float* Wv   = (const float*)d_in[7];
  const float* bv   = (const float*)d_in[8];

  u16* ws  = (u16*)d_ws;
  u16* Wt  = ws;                          // 3 * 512*512 bf16
  u16* Qw  = ws + 786432;                 // [4,8,2048,64] bf16
  u16* Kw  = Qw + 4194304;                // [4,8,2048,64] bf16
  u16* Vtw = Kw + 4194304;                // [4,8,64,2048] bf16

  float* outp  = (float*)d_out;           // [4,2048,512]
  float* attnp = outp + 4194304;          // [4,8,2048,2048]

  wt_kernel  <<<dim3(16,16,3), dim3(32,8), 0, stream>>>(Wq, Wk, Wv, Wt, Wt+262144, Wt+524288);
  proj_kernel<<<dim3(64,4,3),  256,       0, stream>>>(q_in, k_in, v_in, Wt, bq, bk, bv, Qw, Kw, Vtw);
  attn_kernel<<<dim3(16,8,4),  512,       0, stream>>>(Qw, Kw, Vtw, outp, attnp);
}